// Round 6
// baseline (331.577 us; speedup 1.0000x reference)
//
#include <hip/hip_runtime.h>

// Problem: B=1, L=4096, EMBED=1024, 16 heads x 64
static constexpr int L_SEQ = 4096;
static constexpr int EMBED = 1024;
static constexpr int HEADS = 16;
static constexpr int HD    = 64;

typedef unsigned short ushortT;
typedef __attribute__((ext_vector_type(8)))  short short8;   // 8 x bf16 (4 VGPR)
typedef __attribute__((ext_vector_type(4)))  float f32x4;

#define LOG2E 1.4426950408889634f

__device__ __forceinline__ ushortT f2bf(float f) {
  unsigned u = __builtin_bit_cast(unsigned, f);
  u += 0x7fffu + ((u >> 16) & 1u);          // round-to-nearest-even
  return (ushortT)(u >> 16);
}
__device__ __forceinline__ float bf2f(ushortT s) {
  return __builtin_bit_cast(float, ((unsigned)s) << 16);
}

// async global->LDS, 16B/lane; LDS dest is wave-uniform base + lane*16.
#define GLOAD_LDS16(g, l) \
  __builtin_amdgcn_global_load_lds((const __attribute__((address_space(1))) void*)(g), \
                                   (__attribute__((address_space(3))) void*)(l), 16, 0, 0)

// ---------------- fp32 -> bf16 cast, 8 elems/thread ----------------
__global__ void cast_bf16_k(const float* __restrict__ in, ushortT* __restrict__ out, int n8) {
  int i = blockIdx.x * blockDim.x + threadIdx.x;
  if (i >= n8) return;
  const float4* p = (const float4*)in;
  float4 a = p[2 * i], b = p[2 * i + 1];
  uint4 o;
  o.x = (unsigned)f2bf(a.x) | ((unsigned)f2bf(a.y) << 16);
  o.y = (unsigned)f2bf(a.z) | ((unsigned)f2bf(a.w) << 16);
  o.z = (unsigned)f2bf(b.x) | ((unsigned)f2bf(b.y) << 16);
  o.w = (unsigned)f2bf(b.z) | ((unsigned)f2bf(b.w) << 16);
  ((uint4*)out)[i] = o;
}

// fused 4-weight cast (each weight 1M elements), dsts contiguous at out
__global__ void cast4_bf16_k(const float* __restrict__ a, const float* __restrict__ b,
                             const float* __restrict__ c, const float* __restrict__ d,
                             ushortT* __restrict__ out) {
  int idx = blockIdx.x * blockDim.x + threadIdx.x;   // 4 * 131072
  int w = idx >> 17, i = idx & 131071;
  const float* src = (w == 0) ? a : (w == 1) ? b : (w == 2) ? c : d;
  const float4* p = (const float4*)src;
  float4 x = p[2 * i], y = p[2 * i + 1];
  uint4 o;
  o.x = (unsigned)f2bf(x.x) | ((unsigned)f2bf(x.y) << 16);
  o.y = (unsigned)f2bf(x.z) | ((unsigned)f2bf(x.w) << 16);
  o.z = (unsigned)f2bf(y.x) | ((unsigned)f2bf(y.y) << 16);
  o.w = (unsigned)f2bf(y.z) | ((unsigned)f2bf(y.w) << 16);
  ((uint4*)(out + ((size_t)w << 20)))[i] = o;
}

// ---------------- log2(size) ----------------
__global__ void l2size_k(const float* __restrict__ sz, float* __restrict__ l2s, int n) {
  int i = blockIdx.x * blockDim.x + threadIdx.x;
  if (i < n) l2s[i] = __log2f(sz[i]);
}

// ---------------- GEMM: C[M,N] = A[M,K] @ B[N,K]^T + bias ----------------
struct GemmArgs { const ushortT* B; const float* bias; void* dst; int mode; };
// mode 0: Q -> bf16 [h][t][64] * 0.125   mode 1: K -> bf16 [h][t][64]
// mode 2: V -> bf16 [h][64][t] (transposed)      mode 3: fp32 [m][1024]

__global__ __launch_bounds__(256, 3) void gemm_bt_k(
    const ushortT* __restrict__ A, GemmArgs g0, GemmArgs g1, GemmArgs g2)
{
  constexpr int K = 1024;
  __shared__ __align__(16) ushortT As[128 * 64];
  __shared__ __align__(16) ushortT Bs[128 * 64];

  GemmArgs g = (blockIdx.y == 0) ? g0 : ((blockIdx.y == 1) ? g1 : g2);
  const ushortT* __restrict__ Bw = g.B;

  const int tid = threadIdx.x;
  const int wv = tid >> 6, ln = tid & 63;
  const int mb = blockIdx.x & 31, nb = blockIdx.x >> 5;     // 32 x 8 blocks
  const int m0 = mb * 128, n0 = nb * 128;
  const int wr = wv >> 1, wc = wv & 1;
  const int lrow = ln & 15, lq = ln >> 4;

  const int rstg = wv * 8 + (ln >> 3);
  const int ustg = (ln & 7) ^ (ln >> 3);

  f32x4 acc[4][4] = {};

  for (int kt = 0; kt < K; kt += 64) {
#pragma unroll
    for (int i = 0; i < 4; ++i) {
      int r = i * 32 + rstg;
      GLOAD_LDS16(A  + (size_t)(m0 + r) * K + kt + (ustg << 3), As + i * 2048 + wv * 512);
      GLOAD_LDS16(Bw + (size_t)(n0 + r) * K + kt + (ustg << 3), Bs + i * 2048 + wv * 512);
    }
    __syncthreads();
#pragma unroll
    for (int ks = 0; ks < 2; ++ks) {
      short8 a[4], b[4];
#pragma unroll
      for (int mi = 0; mi < 4; ++mi) {
        int ra = wr * 64 + mi * 16 + lrow;
        int u = (ks * 4 + lq) ^ (ra & 7);
        a[mi] = *(const short8*)(As + ra * 64 + (u << 3));
      }
#pragma unroll
      for (int ni = 0; ni < 4; ++ni) {
        int rb = wc * 64 + ni * 16 + lrow;
        int u = (ks * 4 + lq) ^ (rb & 7);
        b[ni] = *(const short8*)(Bs + rb * 64 + (u << 3));
      }
#pragma unroll
      for (int mi = 0; mi < 4; ++mi)
#pragma unroll
        for (int ni = 0; ni < 4; ++ni)
          acc[mi][ni] = __builtin_amdgcn_mfma_f32_16x16x32_bf16(a[mi], b[ni], acc[mi][ni], 0, 0, 0);
    }
    __syncthreads();
  }

  const int mode = g.mode;
  if (mode <= 1) {
    ushortT* dst = (ushortT*)g.dst;
    const float sc = (mode == 0) ? 0.125f : 1.0f;
#pragma unroll
    for (int ni = 0; ni < 4; ++ni) {
      int n = n0 + wc * 64 + ni * 16 + lrow;
      float bsv = g.bias[n];
      size_t base = ((size_t)(n >> 6) * L_SEQ) * HD + (n & 63);
#pragma unroll
      for (int mi = 0; mi < 4; ++mi)
#pragma unroll
        for (int r = 0; r < 4; ++r) {
          int m = m0 + wr * 64 + mi * 16 + lq * 4 + r;
          dst[base + (size_t)m * HD] = f2bf((acc[mi][ni][r] + bsv) * sc);
        }
    }
  } else if (mode == 2) {
    ushortT* dst = (ushortT*)g.dst;
#pragma unroll
    for (int ni = 0; ni < 4; ++ni) {
      int n = n0 + wc * 64 + ni * 16 + lrow;     // n == h*64+hd
      float bsv = g.bias[n];
      size_t base = (size_t)n * L_SEQ;
#pragma unroll
      for (int mi = 0; mi < 4; ++mi)
#pragma unroll
        for (int r = 0; r < 4; ++r) {
          int m = m0 + wr * 64 + mi * 16 + lq * 4 + r;
          dst[base + m] = f2bf(acc[mi][ni][r] + bsv);
        }
    }
  } else {
    float* dst = (float*)g.dst;
#pragma unroll
    for (int ni = 0; ni < 4; ++ni) {
      int n = n0 + wc * 64 + ni * 16 + lrow;
      float bsv = g.bias[n];
#pragma unroll
      for (int mi = 0; mi < 4; ++mi)
#pragma unroll
        for (int r = 0; r < 4; ++r) {
          int m = m0 + wr * 64 + mi * 16 + lq * 4 + r;
          dst[(size_t)m * EMBED + n] = acc[mi][ni][r] + bsv;
        }
    }
  }
}

// ---------------- flash attention (R1-proven 16x16 structure) ----------------
// block = (q-tile of 64, head), 4 waves x 16 q-rows. KV tiles of 64 in LDS,
// XOR-swizzled, now DOUBLE-BUFFERED (prefetch issued before compute; the
// compiler's pre-barrier vmcnt(0) drain makes it race-free). Softmax in
// base-2 with global-f32 log2(size) bias; P transposed via per-wave padded
// LDS. O-rescale skipped when all alphas == 1.0 (bitwise-identical).
__global__ __launch_bounds__(256, 3) void attn_k(
    const ushortT* __restrict__ Q,   // [16][4096][64], pre-scaled by 0.125
    const ushortT* __restrict__ Kb,  // [16][4096][64]
    const ushortT* __restrict__ Vt,  // [16][64][4096]
    const float*   __restrict__ l2s, // [4096] log2(size)
    ushortT* __restrict__ O)         // [4096][1024] bf16
{
  __shared__ __align__(16) ushortT Ks[2][64 * 64];
  __shared__ __align__(16) ushortT Vs[2][64 * 64];
  __shared__ __align__(16) ushortT Ps[4][16 * 72];  // per-wave, +8 pad

  const int tid = threadIdx.x;
  const int wv = tid >> 6, ln = tid & 63;
  const int h = blockIdx.y;
  const int q0 = blockIdx.x * 64;
  const int lrow = ln & 15, lq = ln >> 4;

  short8 qf0, qf1;  // hoisted Q A-fragments (row = lane&15, k contiguous)
  {
    const ushortT* qp = Q + ((size_t)h * L_SEQ + q0 + wv * 16 + lrow) * HD + lq * 8;
    qf0 = *(const short8*)qp;
    qf1 = *(const short8*)(qp + 32);
  }

  f32x4 o[4] = {};
  float mrun[4], lrun[4];
#pragma unroll
  for (int r = 0; r < 4; ++r) { mrun[r] = -1e30f; lrun[r] = 0.f; }

  const int rstg = wv * 8 + (ln >> 3);
  const int ustg = (ln & 7) ^ (ln >> 3);

  auto STAGE = [&](int buf, int t0) {
#pragma unroll
    for (int i = 0; i < 2; ++i) {
      int r = i * 32 + rstg;
      GLOAD_LDS16(Kb + ((size_t)h * L_SEQ + t0 + r) * HD + (ustg << 3), &Ks[buf][i * 2048 + wv * 512]);
      GLOAD_LDS16(Vt + ((size_t)(h * HD + r)) * L_SEQ + t0 + (ustg << 3), &Vs[buf][i * 2048 + wv * 512]);
    }
  };

  STAGE(0, 0);
  __syncthreads();

  for (int t = 0; t < L_SEQ / 64; ++t) {
    const int cur = t & 1;
    if (t < L_SEQ / 64 - 1) STAGE(cur ^ 1, (t + 1) * 64);
    const int t0 = t * 64;
    const ushortT* Kt  = &Ks[cur][0];
    const ushortT* Vtl = &Vs[cur][0];

    // S = Q K^T  (rows q, cols key)
    f32x4 s[4] = {};
    __builtin_amdgcn_s_setprio(1);
#pragma unroll
    for (int ks = 0; ks < 2; ++ks) {
      short8 qa = ks ? qf1 : qf0;
#pragma unroll
      for (int f = 0; f < 4; ++f) {
        int key = f * 16 + lrow;
        int u = (ks * 4 + lq) ^ (key & 7);
        short8 kb = *(const short8*)(Kt + key * 64 + (u << 3));
        s[f] = __builtin_amdgcn_mfma_f32_16x16x32_bf16(qa, kb, s[f], 0, 0, 0);
      }
    }
    __builtin_amdgcn_s_setprio(0);

    // base-2 logits + log2(size_key)
#pragma unroll
    for (int f = 0; f < 4; ++f) {
      float bias = l2s[t0 + f * 16 + lrow];
#pragma unroll
      for (int r = 0; r < 4; ++r)
        s[f][r] = s[f][r] * LOG2E + bias;
    }

    // online softmax; row r lives in 16-lane group (lanes share lq)
    float alpha[4];
    bool noop = true;
#pragma unroll
    for (int r = 0; r < 4; ++r) {
      float t1 = fmaxf(fmaxf(s[0][r], s[1][r]), fmaxf(s[2][r], s[3][r]));
      t1 = fmaxf(t1, __shfl_xor(t1, 1));
      t1 = fmaxf(t1, __shfl_xor(t1, 2));
      t1 = fmaxf(t1, __shfl_xor(t1, 4));
      t1 = fmaxf(t1, __shfl_xor(t1, 8));
      float mnew = fmaxf(mrun[r], t1);
      alpha[r] = __builtin_amdgcn_exp2f(mrun[r] - mnew);
      mrun[r] = mnew;
      float rs = 0.f;
#pragma unroll
      for (int f = 0; f < 4; ++f) {
        float pv = __builtin_amdgcn_exp2f(s[f][r] - mnew);
        s[f][r] = pv;
        rs += pv;
      }
      rs += __shfl_xor(rs, 1);
      rs += __shfl_xor(rs, 2);
      rs += __shfl_xor(rs, 4);
      rs += __shfl_xor(rs, 8);
      lrun[r] = lrun[r] * alpha[r] + rs;
      noop = noop && (alpha[r] == 1.0f);
    }
    if (!__all(noop)) {              // skip O-rescale when all alphas == 1
#pragma unroll
      for (int df = 0; df < 4; ++df)
#pragma unroll
        for (int r = 0; r < 4; ++r) o[df][r] *= alpha[r];
    }

    // P -> per-wave LDS (C layout in, A layout out), padded to 72 shorts/row
    ushortT* pb = &Ps[wv][0];
#pragma unroll
    for (int f = 0; f < 4; ++f)
#pragma unroll
      for (int r = 0; r < 4; ++r)
        pb[(lq * 4 + r) * 72 + f * 16 + lrow] = f2bf(s[f][r]);

    asm volatile("s_waitcnt lgkmcnt(0)" ::: "memory");  // cross-lane LDS dep
    __builtin_amdgcn_sched_barrier(0);

    short8 pa0 = *(const short8*)(pb + lrow * 72 + lq * 8);
    short8 pa1 = *(const short8*)(pb + lrow * 72 + 32 + lq * 8);

    // O += P @ V   (B operand from transposed-V tile: row=d, k=key)
    __builtin_amdgcn_s_setprio(1);
#pragma unroll
    for (int ks = 0; ks < 2; ++ks) {
      short8 pa = ks ? pa1 : pa0;
#pragma unroll
      for (int df = 0; df < 4; ++df) {
        int d = df * 16 + lrow;
        int u = (ks * 4 + lq) ^ (d & 7);
        short8 vb = *(const short8*)(Vtl + d * 64 + (u << 3));
        o[df] = __builtin_amdgcn_mfma_f32_16x16x32_bf16(pa, vb, o[df], 0, 0, 0);
      }
    }
    __builtin_amdgcn_s_setprio(0);

    __syncthreads();
  }

  // epilogue: divide by softmax denom, store bf16 [t][h*64+d]
#pragma unroll
  for (int df = 0; df < 4; ++df)
#pragma unroll
    for (int r = 0; r < 4; ++r) {
      int q = q0 + wv * 16 + lq * 4 + r;
      O[(size_t)q * EMBED + h * HD + df * 16 + lrow] = f2bf(o[df][r] / lrun[r]);
    }
}

// ---------------- metric = mean over heads of K ----------------
__global__ void metric_k(const ushortT* __restrict__ Kb, float* __restrict__ out) {
  int idx = blockIdx.x * blockDim.x + threadIdx.x;   // t*8 + c8
  int t = idx >> 3, c8 = idx & 7;
  float acc[8] = {};
#pragma unroll
  for (int h = 0; h < HEADS; ++h) {
    short8 v = *(const short8*)(Kb + ((size_t)h * L_SEQ + t) * HD + c8 * 8);
#pragma unroll
    for (int j = 0; j < 8; ++j) acc[j] += bf2f((ushortT)v[j]);
  }
  float* dst = out + (size_t)t * HD + c8 * 8;
#pragma unroll
  for (int j = 0; j < 8; ++j) dst[j] = acc[j] * (1.0f / 16.0f);
}

extern "C" void kernel_launch(void* const* d_in, const int* in_sizes, int n_in,
                              void* d_out, int out_size, void* d_ws, size_t ws_size,
                              hipStream_t stream) {
  const float* hs = (const float*)d_in[0];
  const float* sz = (const float*)d_in[1];
  const float* wq = (const float*)d_in[2];
  const float* bq = (const float*)d_in[3];
  const float* wk = (const float*)d_in[4];
  const float* bk = (const float*)d_in[5];
  const float* wv = (const float*)d_in[6];
  const float* bv = (const float*)d_in[7];
  const float* wo = (const float*)d_in[8];
  const float* bo = (const float*)d_in[9];

  char* ws = (char*)d_ws;
  ushortT* hs_b = (ushortT*)(ws);                 // [4096][1024] bf16
  ushortT* wq_b = (ushortT*)(ws + (8u << 20));    // 4 weights bf16 (contiguous)
  ushortT* wk_b = wq_b + (1u << 20);
  ushortT* wv_b = wq_b + (2u << 20);
  ushortT* wo_b = wq_b + (3u << 20);
  ushortT* q_b  = (ushortT*)(ws + (16u << 20));   // [16][4096][64]
  ushortT* k_b  = (ushortT*)(ws + (24u << 20));   // [16][4096][64]
  ushortT* vt_b = (ushortT*)(ws + (32u << 20));   // [16][64][4096]
  ushortT* at_b = (ushortT*)(ws + (40u << 20));   // [4096][1024]
  float*   l2s  = (float*)(ws + (48u << 20));     // [4096]

  float* outp    = (float*)d_out;
  float* metricp = outp + (size_t)L_SEQ * EMBED;

  cast_bf16_k<<<L_SEQ * EMBED / 8 / 256, 256, 0, stream>>>(hs, hs_b, L_SEQ * EMBED / 8);
  cast4_bf16_k<<<2048, 256, 0, stream>>>(wq, wk, wv, wo, wq_b);
  l2size_k<<<L_SEQ / 256, 256, 0, stream>>>(sz, l2s, L_SEQ);

  GemmArgs aq{wq_b, bq, (void*)q_b, 0};
  GemmArgs ak{wk_b, bk, (void*)k_b, 1};
  GemmArgs av{wv_b, bv, (void*)vt_b, 2};
  gemm_bt_k<<<dim3(256, 3), 256, 0, stream>>>(hs_b, aq, ak, av);   // fused QKV

  metric_k<<<L_SEQ * 8 / 256, 256, 0, stream>>>(k_b, metricp);

  attn_k<<<dim3(64, 16), 256, 0, stream>>>(q_b, k_b, vt_b, l2s, at_b);

  GemmArgs ao{wo_b, bo, (void*)outp, 3};
  gemm_bt_k<<<dim3(256, 1), 256, 0, stream>>>(at_b, ao, ao, ao);   // O projection
}

// Round 7
// 291.634 us; speedup vs baseline: 1.1370x; 1.1370x over previous
//
#include <hip/hip_runtime.h>

// Problem: B=1, L=4096, EMBED=1024, 16 heads x 64
static constexpr int L_SEQ = 4096;
static constexpr int EMBED = 1024;
static constexpr int HEADS = 16;
static constexpr int HD    = 64;

typedef unsigned short ushortT;
typedef __attribute__((ext_vector_type(8)))  short short8;   // 8 x bf16 (4 VGPR)
typedef __attribute__((ext_vector_type(4)))  float f32x4;

#define LOG2E 1.4426950408889634f

__device__ __forceinline__ ushortT f2bf(float f) {
  unsigned u = __builtin_bit_cast(unsigned, f);
  u += 0x7fffu + ((u >> 16) & 1u);          // round-to-nearest-even
  return (ushortT)(u >> 16);
}
__device__ __forceinline__ float bf2f(ushortT s) {
  return __builtin_bit_cast(float, ((unsigned)s) << 16);
}

// async global->LDS, 16B/lane; LDS dest is wave-uniform base + lane*16.
#define GLOAD_LDS16(g, l) \
  __builtin_amdgcn_global_load_lds((const __attribute__((address_space(1))) void*)(g), \
                                   (__attribute__((address_space(3))) void*)(l), 16, 0, 0)

// ---------------- fp32 -> bf16 cast, 8 elems/thread ----------------
__global__ void cast_bf16_k(const float* __restrict__ in, ushortT* __restrict__ out, int n8) {
  int i = blockIdx.x * blockDim.x + threadIdx.x;
  if (i >= n8) return;
  const float4* p = (const float4*)in;
  float4 a = p[2 * i], b = p[2 * i + 1];
  uint4 o;
  o.x = (unsigned)f2bf(a.x) | ((unsigned)f2bf(a.y) << 16);
  o.y = (unsigned)f2bf(a.z) | ((unsigned)f2bf(a.w) << 16);
  o.z = (unsigned)f2bf(b.x) | ((unsigned)f2bf(b.y) << 16);
  o.w = (unsigned)f2bf(b.z) | ((unsigned)f2bf(b.w) << 16);
  ((uint4*)out)[i] = o;
}

// fused 4-weight cast (each weight 1M elements), dsts contiguous at out
__global__ void cast4_bf16_k(const float* __restrict__ a, const float* __restrict__ b,
                             const float* __restrict__ c, const float* __restrict__ d,
                             ushortT* __restrict__ out) {
  int idx = blockIdx.x * blockDim.x + threadIdx.x;   // 4 * 131072
  int w = idx >> 17, i = idx & 131071;
  const float* src = (w == 0) ? a : (w == 1) ? b : (w == 2) ? c : d;
  const float4* p = (const float4*)src;
  float4 x = p[2 * i], y = p[2 * i + 1];
  uint4 o;
  o.x = (unsigned)f2bf(x.x) | ((unsigned)f2bf(x.y) << 16);
  o.y = (unsigned)f2bf(x.z) | ((unsigned)f2bf(x.w) << 16);
  o.z = (unsigned)f2bf(y.x) | ((unsigned)f2bf(y.y) << 16);
  o.w = (unsigned)f2bf(y.z) | ((unsigned)f2bf(y.w) << 16);
  ((uint4*)(out + ((size_t)w << 20)))[i] = o;
}

// ---------------- log2(size) ----------------
__global__ void l2size_k(const float* __restrict__ sz, float* __restrict__ l2s, int n) {
  int i = blockIdx.x * blockDim.x + threadIdx.x;
  if (i < n) l2s[i] = __log2f(sz[i]);
}

// ---------------- GEMM: C[M,N] = A[M,K] @ B[N,K]^T + bias ----------------
struct GemmArgs { const ushortT* B; const float* bias; void* dst; int mode; };
// mode 0: Q -> bf16 [h][t][64] * 0.125   mode 1: K -> bf16 [h][t][64]
// mode 2: V -> bf16 [h][64][t] (transposed)      mode 3: fp32 [m][1024]

__global__ __launch_bounds__(256, 3) void gemm_bt_k(
    const ushortT* __restrict__ A, GemmArgs g0, GemmArgs g1, GemmArgs g2)
{
  constexpr int K = 1024;
  __shared__ __align__(16) ushortT As[128 * 64];
  __shared__ __align__(16) ushortT Bs[128 * 64];

  GemmArgs g = (blockIdx.y == 0) ? g0 : ((blockIdx.y == 1) ? g1 : g2);
  const ushortT* __restrict__ Bw = g.B;

  const int tid = threadIdx.x;
  const int wv = tid >> 6, ln = tid & 63;
  const int mb = blockIdx.x & 31, nb = blockIdx.x >> 5;     // 32 x 8 blocks
  const int m0 = mb * 128, n0 = nb * 128;
  const int wr = wv >> 1, wc = wv & 1;
  const int lrow = ln & 15, lq = ln >> 4;

  const int rstg = wv * 8 + (ln >> 3);
  const int ustg = (ln & 7) ^ (ln >> 3);

  f32x4 acc[4][4] = {};

  for (int kt = 0; kt < K; kt += 64) {
#pragma unroll
    for (int i = 0; i < 4; ++i) {
      int r = i * 32 + rstg;
      GLOAD_LDS16(A  + (size_t)(m0 + r) * K + kt + (ustg << 3), As + i * 2048 + wv * 512);
      GLOAD_LDS16(Bw + (size_t)(n0 + r) * K + kt + (ustg << 3), Bs + i * 2048 + wv * 512);
    }
    __syncthreads();
#pragma unroll
    for (int ks = 0; ks < 2; ++ks) {
      short8 a[4], b[4];
#pragma unroll
      for (int mi = 0; mi < 4; ++mi) {
        int ra = wr * 64 + mi * 16 + lrow;
        int u = (ks * 4 + lq) ^ (ra & 7);
        a[mi] = *(const short8*)(As + ra * 64 + (u << 3));
      }
#pragma unroll
      for (int ni = 0; ni < 4; ++ni) {
        int rb = wc * 64 + ni * 16 + lrow;
        int u = (ks * 4 + lq) ^ (rb & 7);
        b[ni] = *(const short8*)(Bs + rb * 64 + (u << 3));
      }
#pragma unroll
      for (int mi = 0; mi < 4; ++mi)
#pragma unroll
        for (int ni = 0; ni < 4; ++ni)
          acc[mi][ni] = __builtin_amdgcn_mfma_f32_16x16x32_bf16(a[mi], b[ni], acc[mi][ni], 0, 0, 0);
    }
    __syncthreads();
  }

  const int mode = g.mode;
  if (mode <= 1) {
    ushortT* dst = (ushortT*)g.dst;
    const float sc = (mode == 0) ? 0.125f : 1.0f;
#pragma unroll
    for (int ni = 0; ni < 4; ++ni) {
      int n = n0 + wc * 64 + ni * 16 + lrow;
      float bsv = g.bias[n];
      size_t base = ((size_t)(n >> 6) * L_SEQ) * HD + (n & 63);
#pragma unroll
      for (int mi = 0; mi < 4; ++mi)
#pragma unroll
        for (int r = 0; r < 4; ++r) {
          int m = m0 + wr * 64 + mi * 16 + lq * 4 + r;
          dst[base + (size_t)m * HD] = f2bf((acc[mi][ni][r] + bsv) * sc);
        }
    }
  } else if (mode == 2) {
    ushortT* dst = (ushortT*)g.dst;
#pragma unroll
    for (int ni = 0; ni < 4; ++ni) {
      int n = n0 + wc * 64 + ni * 16 + lrow;     // n == h*64+hd
      float bsv = g.bias[n];
      size_t base = (size_t)n * L_SEQ;
#pragma unroll
      for (int mi = 0; mi < 4; ++mi)
#pragma unroll
        for (int r = 0; r < 4; ++r) {
          int m = m0 + wr * 64 + mi * 16 + lq * 4 + r;
          dst[base + m] = f2bf(acc[mi][ni][r] + bsv);
        }
    }
  } else {
    float* dst = (float*)g.dst;
#pragma unroll
    for (int ni = 0; ni < 4; ++ni) {
      int n = n0 + wc * 64 + ni * 16 + lrow;
      float bsv = g.bias[n];
#pragma unroll
      for (int mi = 0; mi < 4; ++mi)
#pragma unroll
        for (int r = 0; r < 4; ++r) {
          int m = m0 + wr * 64 + mi * 16 + lq * 4 + r;
          dst[(size_t)m * EMBED + n] = acc[mi][ni][r] + bsv;
        }
    }
  }
}

// ---------------- flash attention (R1 16x16 structure, single-buffered) -------
// 1024 blocks (64 q-tiles x 16 heads) with XCD head-clustering swizzle:
// linear id -> xcd = id&7 serves heads {2*xcd, 2*xcd+1}, so each XCD's L2
// holds a 2MB K/V working set (vs 16MB un-swizzled). LDS 25600B -> 6 blocks/CU
// capacity, 4 resident (grid-capped) = the R1 occupancy that beat R6's dbuf.
// Softmax base-2 with global-f32 log2(size) bias; P transposed via per-wave
// padded LDS; O-rescale skipped when all alphas == 1.0 (bitwise-identical).
__global__ __launch_bounds__(256, 4) void attn_k(
    const ushortT* __restrict__ Q,   // [16][4096][64], pre-scaled by 0.125
    const ushortT* __restrict__ Kb,  // [16][4096][64]
    const ushortT* __restrict__ Vt,  // [16][64][4096]
    const float*   __restrict__ l2s, // [4096] log2(size)
    ushortT* __restrict__ O)         // [4096][1024] bf16
{
  __shared__ __align__(16) ushortT Ks[64 * 64];
  __shared__ __align__(16) ushortT Vs[64 * 64];
  __shared__ __align__(16) ushortT Ps[4][16 * 72];  // per-wave, +8 pad

  const int id = blockIdx.x;                 // 0..1023
  const int xcd = id & 7, s = id >> 3;
  const int h  = xcd * 2 + (s >> 6);         // head (2 per XCD)
  const int q0 = (s & 63) * 64;              // q-tile base

  const int tid = threadIdx.x;
  const int wv = tid >> 6, ln = tid & 63;
  const int lrow = ln & 15, lq = ln >> 4;

  short8 qf0, qf1;  // hoisted Q A-fragments (row = lane&15, k contiguous)
  {
    const ushortT* qp = Q + ((size_t)h * L_SEQ + q0 + wv * 16 + lrow) * HD + lq * 8;
    qf0 = *(const short8*)qp;
    qf1 = *(const short8*)(qp + 32);
  }

  f32x4 o[4] = {};
  float mrun[4], lrun[4];
#pragma unroll
  for (int r = 0; r < 4; ++r) { mrun[r] = -1e30f; lrun[r] = 0.f; }

  const int rstg = wv * 8 + (ln >> 3);
  const int ustg = (ln & 7) ^ (ln >> 3);

  for (int t = 0; t < L_SEQ / 64; ++t) {
    const int t0 = t * 64;
#pragma unroll
    for (int i = 0; i < 2; ++i) {
      int r = i * 32 + rstg;
      GLOAD_LDS16(Kb + ((size_t)h * L_SEQ + t0 + r) * HD + (ustg << 3), Ks + i * 2048 + wv * 512);
      GLOAD_LDS16(Vt + ((size_t)(h * HD + r)) * L_SEQ + t0 + (ustg << 3), Vs + i * 2048 + wv * 512);
    }
    __syncthreads();

    // S = Q K^T  (rows q, cols key)
    f32x4 sfr[4] = {};
    __builtin_amdgcn_s_setprio(1);
#pragma unroll
    for (int ks = 0; ks < 2; ++ks) {
      short8 qa = ks ? qf1 : qf0;
#pragma unroll
      for (int f = 0; f < 4; ++f) {
        int key = f * 16 + lrow;
        int u = (ks * 4 + lq) ^ (key & 7);
        short8 kb = *(const short8*)(Ks + key * 64 + (u << 3));
        sfr[f] = __builtin_amdgcn_mfma_f32_16x16x32_bf16(qa, kb, sfr[f], 0, 0, 0);
      }
    }
    __builtin_amdgcn_s_setprio(0);

    // base-2 logits + log2(size_key)
#pragma unroll
    for (int f = 0; f < 4; ++f) {
      float bias = l2s[t0 + f * 16 + lrow];
#pragma unroll
      for (int r = 0; r < 4; ++r)
        sfr[f][r] = sfr[f][r] * LOG2E + bias;
    }

    // online softmax; row r lives in 16-lane group (lanes share lq)
    float alpha[4];
    bool noop = true;
#pragma unroll
    for (int r = 0; r < 4; ++r) {
      float t1 = fmaxf(fmaxf(sfr[0][r], sfr[1][r]), fmaxf(sfr[2][r], sfr[3][r]));
      t1 = fmaxf(t1, __shfl_xor(t1, 1));
      t1 = fmaxf(t1, __shfl_xor(t1, 2));
      t1 = fmaxf(t1, __shfl_xor(t1, 4));
      t1 = fmaxf(t1, __shfl_xor(t1, 8));
      float mnew = fmaxf(mrun[r], t1);
      alpha[r] = __builtin_amdgcn_exp2f(mrun[r] - mnew);
      mrun[r] = mnew;
      float rs = 0.f;
#pragma unroll
      for (int f = 0; f < 4; ++f) {
        float pv = __builtin_amdgcn_exp2f(sfr[f][r] - mnew);
        sfr[f][r] = pv;
        rs += pv;
      }
      rs += __shfl_xor(rs, 1);
      rs += __shfl_xor(rs, 2);
      rs += __shfl_xor(rs, 4);
      rs += __shfl_xor(rs, 8);
      lrun[r] = lrun[r] * alpha[r] + rs;
      noop = noop && (alpha[r] == 1.0f);
    }
    if (!__all(noop)) {              // skip O-rescale when all alphas == 1
#pragma unroll
      for (int df = 0; df < 4; ++df)
#pragma unroll
        for (int r = 0; r < 4; ++r) o[df][r] *= alpha[r];
    }

    // P -> per-wave LDS (C layout in, A layout out), padded to 72 shorts/row
    ushortT* pb = &Ps[wv][0];
#pragma unroll
    for (int f = 0; f < 4; ++f)
#pragma unroll
      for (int r = 0; r < 4; ++r)
        pb[(lq * 4 + r) * 72 + f * 16 + lrow] = f2bf(sfr[f][r]);

    asm volatile("s_waitcnt lgkmcnt(0)" ::: "memory");  // cross-lane LDS dep
    __builtin_amdgcn_sched_barrier(0);

    short8 pa0 = *(const short8*)(pb + lrow * 72 + lq * 8);
    short8 pa1 = *(const short8*)(pb + lrow * 72 + 32 + lq * 8);

    // O += P @ V   (B operand from transposed-V tile: row=d, k=key)
    __builtin_amdgcn_s_setprio(1);
#pragma unroll
    for (int ks = 0; ks < 2; ++ks) {
      short8 pa = ks ? pa1 : pa0;
#pragma unroll
      for (int df = 0; df < 4; ++df) {
        int d = df * 16 + lrow;
        int u = (ks * 4 + lq) ^ (d & 7);
        short8 vb = *(const short8*)(Vs + d * 64 + (u << 3));
        o[df] = __builtin_amdgcn_mfma_f32_16x16x32_bf16(pa, vb, o[df], 0, 0, 0);
      }
    }
    __builtin_amdgcn_s_setprio(0);

    __syncthreads();
  }

  // epilogue: divide by softmax denom, store bf16 [t][h*64+d]
#pragma unroll
  for (int df = 0; df < 4; ++df)
#pragma unroll
    for (int r = 0; r < 4; ++r) {
      int q = q0 + wv * 16 + lq * 4 + r;
      O[(size_t)q * EMBED + h * HD + df * 16 + lrow] = f2bf(o[df][r] / lrun[r]);
    }
}

// ---------------- metric = mean over heads of K ----------------
__global__ void metric_k(const ushortT* __restrict__ Kb, float* __restrict__ out) {
  int idx = blockIdx.x * blockDim.x + threadIdx.x;   // t*8 + c8
  int t = idx >> 3, c8 = idx & 7;
  float acc[8] = {};
#pragma unroll
  for (int h = 0; h < HEADS; ++h) {
    short8 v = *(const short8*)(Kb + ((size_t)h * L_SEQ + t) * HD + c8 * 8);
#pragma unroll
    for (int j = 0; j < 8; ++j) acc[j] += bf2f((ushortT)v[j]);
  }
  float* dst = out + (size_t)t * HD + c8 * 8;
#pragma unroll
  for (int j = 0; j < 8; ++j) dst[j] = acc[j] * (1.0f / 16.0f);
}

extern "C" void kernel_launch(void* const* d_in, const int* in_sizes, int n_in,
                              void* d_out, int out_size, void* d_ws, size_t ws_size,
                              hipStream_t stream) {
  const float* hs = (const float*)d_in[0];
  const float* sz = (const float*)d_in[1];
  const float* wq = (const float*)d_in[2];
  const float* bq = (const float*)d_in[3];
  const float* wk = (const float*)d_in[4];
  const float* bk = (const float*)d_in[5];
  const float* wv = (const float*)d_in[6];
  const float* bv = (const float*)d_in[7];
  const float* wo = (const float*)d_in[8];
  const float* bo = (const float*)d_in[9];

  char* ws = (char*)d_ws;
  ushortT* hs_b = (ushortT*)(ws);                 // [4096][1024] bf16
  ushortT* wq_b = (ushortT*)(ws + (8u << 20));    // 4 weights bf16 (contiguous)
  ushortT* wk_b = wq_b + (1u << 20);
  ushortT* wv_b = wq_b + (2u << 20);
  ushortT* wo_b = wq_b + (3u << 20);
  ushortT* q_b  = (ushortT*)(ws + (16u << 20));   // [16][4096][64]
  ushortT* k_b  = (ushortT*)(ws + (24u << 20));   // [16][4096][64]
  ushortT* vt_b = (ushortT*)(ws + (32u << 20));   // [16][64][4096]
  ushortT* at_b = (ushortT*)(ws + (40u << 20));   // [4096][1024]
  float*   l2s  = (float*)(ws + (48u << 20));     // [4096]

  float* outp    = (float*)d_out;
  float* metricp = outp + (size_t)L_SEQ * EMBED;

  cast_bf16_k<<<L_SEQ * EMBED / 8 / 256, 256, 0, stream>>>(hs, hs_b, L_SEQ * EMBED / 8);
  cast4_bf16_k<<<2048, 256, 0, stream>>>(wq, wk, wv, wo, wq_b);
  l2size_k<<<L_SEQ / 256, 256, 0, stream>>>(sz, l2s, L_SEQ);

  GemmArgs aq{wq_b, bq, (void*)q_b, 0};
  GemmArgs ak{wk_b, bk, (void*)k_b, 1};
  GemmArgs av{wv_b, bv, (void*)vt_b, 2};
  gemm_bt_k<<<dim3(256, 3), 256, 0, stream>>>(hs_b, aq, ak, av);   // fused QKV

  metric_k<<<L_SEQ * 8 / 256, 256, 0, stream>>>(k_b, metricp);

  attn_k<<<1024, 256, 0, stream>>>(q_b, k_b, vt_b, l2s, at_b);

  GemmArgs ao{wo_b, bo, (void*)outp, 3};
  gemm_bt_k<<<dim3(256, 1), 256, 0, stream>>>(at_b, ao, ao, ao);   // O projection
}

// Round 9
// 236.522 us; speedup vs baseline: 1.4019x; 1.2330x over previous
//
#include <hip/hip_runtime.h>

// Problem: B=1, L=4096, EMBED=1024, 16 heads x 64
static constexpr int L_SEQ = 4096;
static constexpr int EMBED = 1024;
static constexpr int HEADS = 16;
static constexpr int HD    = 64;

typedef unsigned short ushortT;
typedef __attribute__((ext_vector_type(8)))  short short8;   // 8 x bf16 (4 VGPR)
typedef __attribute__((ext_vector_type(4)))  float f32x4;

#define LOG2E 1.4426950408889634f

__device__ __forceinline__ ushortT f2bf(float f) {
  unsigned u = __builtin_bit_cast(unsigned, f);
  u += 0x7fffu + ((u >> 16) & 1u);          // round-to-nearest-even
  return (ushortT)(u >> 16);
}
__device__ __forceinline__ float bf2f(ushortT s) {
  return __builtin_bit_cast(float, ((unsigned)s) << 16);
}

// ---- DPP 16-lane butterfly reduction (VALU pipe, replaces ds_swizzle shfl) ----
// ctrls: 0xB1 quad_perm xor1, 0x4E quad_perm xor2, 0x141 row_half_mirror
// (lane^7), 0x140 row_mirror (lane^15). After xor1+xor2 the partials are
// quad-uniform, so ^7 / ^15 deliver the same partner values as ^4 / ^8 ->
// bitwise-identical to the __shfl_xor(1,2,4,8) version.
// dpp_ctrl must be an integer-constant expression -> template parameter.
template <int CTRL>
__device__ __forceinline__ float fmax_dpp(float x) {
  int v = __builtin_amdgcn_mov_dpp(__builtin_bit_cast(int, x), CTRL, 0xF, 0xF, true);
  return fmaxf(x, __builtin_bit_cast(float, v));
}
template <int CTRL>
__device__ __forceinline__ float fadd_dpp(float x) {
  int v = __builtin_amdgcn_mov_dpp(__builtin_bit_cast(int, x), CTRL, 0xF, 0xF, true);
  return x + __builtin_bit_cast(float, v);
}
__device__ __forceinline__ float red16_max(float x) {
  x = fmax_dpp<0xB1>(x); x = fmax_dpp<0x4E>(x);
  x = fmax_dpp<0x141>(x); x = fmax_dpp<0x140>(x);
  return x;
}
__device__ __forceinline__ float red16_sum(float x) {
  x = fadd_dpp<0xB1>(x); x = fadd_dpp<0x4E>(x);
  x = fadd_dpp<0x141>(x); x = fadd_dpp<0x140>(x);
  return x;
}

// async global->LDS, 16B/lane; LDS dest is wave-uniform base + lane*16.
#define GLOAD_LDS16(g, l) \
  __builtin_amdgcn_global_load_lds((const __attribute__((address_space(1))) void*)(g), \
                                   (__attribute__((address_space(3))) void*)(l), 16, 0, 0)

// ---------------- fp32 -> bf16 cast, 8 elems/thread ----------------
__global__ void cast_bf16_k(const float* __restrict__ in, ushortT* __restrict__ out, int n8) {
  int i = blockIdx.x * blockDim.x + threadIdx.x;
  if (i >= n8) return;
  const float4* p = (const float4*)in;
  float4 a = p[2 * i], b = p[2 * i + 1];
  uint4 o;
  o.x = (unsigned)f2bf(a.x) | ((unsigned)f2bf(a.y) << 16);
  o.y = (unsigned)f2bf(a.z) | ((unsigned)f2bf(a.w) << 16);
  o.z = (unsigned)f2bf(b.x) | ((unsigned)f2bf(b.y) << 16);
  o.w = (unsigned)f2bf(b.z) | ((unsigned)f2bf(b.w) << 16);
  ((uint4*)out)[i] = o;
}

// fused 4-weight cast (each weight 1M elements), dsts contiguous at out
__global__ void cast4_bf16_k(const float* __restrict__ a, const float* __restrict__ b,
                             const float* __restrict__ c, const float* __restrict__ d,
                             ushortT* __restrict__ out) {
  int idx = blockIdx.x * blockDim.x + threadIdx.x;   // 4 * 131072
  int w = idx >> 17, i = idx & 131071;
  const float* src = (w == 0) ? a : (w == 1) ? b : (w == 2) ? c : d;
  const float4* p = (const float4*)src;
  float4 x = p[2 * i], y = p[2 * i + 1];
  uint4 o;
  o.x = (unsigned)f2bf(x.x) | ((unsigned)f2bf(x.y) << 16);
  o.y = (unsigned)f2bf(x.z) | ((unsigned)f2bf(x.w) << 16);
  o.z = (unsigned)f2bf(y.x) | ((unsigned)f2bf(y.y) << 16);
  o.w = (unsigned)f2bf(y.z) | ((unsigned)f2bf(y.w) << 16);
  ((uint4*)(out + ((size_t)w << 20)))[i] = o;
}

// ---------------- log2(size) ----------------
__global__ void l2size_k(const float* __restrict__ sz, float* __restrict__ l2s, int n) {
  int i = blockIdx.x * blockDim.x + threadIdx.x;
  if (i < n) l2s[i] = __log2f(sz[i]);
}

// ---------------- GEMM: C[M,N] = A[M,K] @ B[N,K]^T + bias ----------------
struct GemmArgs { const ushortT* B; const float* bias; void* dst; int mode; };
// mode 0: Q -> bf16 [h][t][64] * 0.125   mode 1: K -> bf16 [h][t][64]
// mode 2: V -> bf16 [h][64][t] (transposed)      mode 3: fp32 [m][1024]

__global__ __launch_bounds__(256, 3) void gemm_bt_k(
    const ushortT* __restrict__ A, GemmArgs g0, GemmArgs g1, GemmArgs g2)
{
  constexpr int K = 1024;
  __shared__ __align__(16) ushortT As[128 * 64];
  __shared__ __align__(16) ushortT Bs[128 * 64];

  GemmArgs g = (blockIdx.y == 0) ? g0 : ((blockIdx.y == 1) ? g1 : g2);
  const ushortT* __restrict__ Bw = g.B;

  const int tid = threadIdx.x;
  const int wv = tid >> 6, ln = tid & 63;
  const int mb = blockIdx.x & 31, nb = blockIdx.x >> 5;     // 32 x 8 blocks
  const int m0 = mb * 128, n0 = nb * 128;
  const int wr = wv >> 1, wc = wv & 1;
  const int lrow = ln & 15, lq = ln >> 4;

  const int rstg = wv * 8 + (ln >> 3);
  const int ustg = (ln & 7) ^ (ln >> 3);

  f32x4 acc[4][4] = {};

  for (int kt = 0; kt < K; kt += 64) {
#pragma unroll
    for (int i = 0; i < 4; ++i) {
      int r = i * 32 + rstg;
      GLOAD_LDS16(A  + (size_t)(m0 + r) * K + kt + (ustg << 3), As + i * 2048 + wv * 512);
      GLOAD_LDS16(Bw + (size_t)(n0 + r) * K + kt + (ustg << 3), Bs + i * 2048 + wv * 512);
    }
    __syncthreads();
#pragma unroll
    for (int ks = 0; ks < 2; ++ks) {
      short8 a[4], b[4];
#pragma unroll
      for (int mi = 0; mi < 4; ++mi) {
        int ra = wr * 64 + mi * 16 + lrow;
        int u = (ks * 4 + lq) ^ (ra & 7);
        a[mi] = *(const short8*)(As + ra * 64 + (u << 3));
      }
#pragma unroll
      for (int ni = 0; ni < 4; ++ni) {
        int rb = wc * 64 + ni * 16 + lrow;
        int u = (ks * 4 + lq) ^ (rb & 7);
        b[ni] = *(const short8*)(Bs + rb * 64 + (u << 3));
      }
#pragma unroll
      for (int mi = 0; mi < 4; ++mi)
#pragma unroll
        for (int ni = 0; ni < 4; ++ni)
          acc[mi][ni] = __builtin_amdgcn_mfma_f32_16x16x32_bf16(a[mi], b[ni], acc[mi][ni], 0, 0, 0);
    }
    __syncthreads();
  }

  const int mode = g.mode;
  if (mode <= 1) {
    ushortT* dst = (ushortT*)g.dst;
    const float sc = (mode == 0) ? 0.125f : 1.0f;
#pragma unroll
    for (int ni = 0; ni < 4; ++ni) {
      int n = n0 + wc * 64 + ni * 16 + lrow;
      float bsv = g.bias[n];
      size_t base = ((size_t)(n >> 6) * L_SEQ) * HD + (n & 63);
#pragma unroll
      for (int mi = 0; mi < 4; ++mi)
#pragma unroll
        for (int r = 0; r < 4; ++r) {
          int m = m0 + wr * 64 + mi * 16 + lq * 4 + r;
          dst[base + (size_t)m * HD] = f2bf((acc[mi][ni][r] + bsv) * sc);
        }
    }
  } else if (mode == 2) {
    ushortT* dst = (ushortT*)g.dst;
#pragma unroll
    for (int ni = 0; ni < 4; ++ni) {
      int n = n0 + wc * 64 + ni * 16 + lrow;     // n == h*64+hd
      float bsv = g.bias[n];
      size_t base = (size_t)n * L_SEQ;
#pragma unroll
      for (int mi = 0; mi < 4; ++mi)
#pragma unroll
        for (int r = 0; r < 4; ++r) {
          int m = m0 + wr * 64 + mi * 16 + lq * 4 + r;
          dst[base + m] = f2bf(acc[mi][ni][r] + bsv);
        }
    }
  } else {
    float* dst = (float*)g.dst;
#pragma unroll
    for (int ni = 0; ni < 4; ++ni) {
      int n = n0 + wc * 64 + ni * 16 + lrow;
      float bsv = g.bias[n];
#pragma unroll
      for (int mi = 0; mi < 4; ++mi)
#pragma unroll
        for (int r = 0; r < 4; ++r) {
          int m = m0 + wr * 64 + mi * 16 + lq * 4 + r;
          dst[(size_t)m * EMBED + n] = acc[mi][ni][r] + bsv;
        }
    }
  }
}

// ---------------- flash attention (R1 16x16 structure, single-buffered) -------
// 1024 blocks, XCD head-clustering swizzle (FETCH 70->12MB, R7). Softmax
// reductions via DPP butterfly on the VALU pipe: the 8 ds_swizzle ops/row
// (~400-600 serial cyc) become 8 DPP ops (~30-60 cyc) — bitwise-identical
// values. O-rescale skipped when all alphas == 1.0.
__global__ __launch_bounds__(256, 4) void attn_k(
    const ushortT* __restrict__ Q,   // [16][4096][64], pre-scaled by 0.125
    const ushortT* __restrict__ Kb,  // [16][4096][64]
    const ushortT* __restrict__ Vt,  // [16][64][4096]
    const float*   __restrict__ l2s, // [4096] log2(size)
    ushortT* __restrict__ O)         // [4096][1024] bf16
{
  __shared__ __align__(16) ushortT Ks[64 * 64];
  __shared__ __align__(16) ushortT Vs[64 * 64];
  __shared__ __align__(16) ushortT Ps[4][16 * 72];  // per-wave, +8 pad

  const int id = blockIdx.x;                 // 0..1023
  const int xcd = id & 7, s = id >> 3;
  const int h  = xcd * 2 + (s >> 6);         // head (2 per XCD)
  const int q0 = (s & 63) * 64;              // q-tile base

  const int tid = threadIdx.x;
  const int wv = tid >> 6, ln = tid & 63;
  const int lrow = ln & 15, lq = ln >> 4;

  short8 qf0, qf1;  // hoisted Q A-fragments (row = lane&15, k contiguous)
  {
    const ushortT* qp = Q + ((size_t)h * L_SEQ + q0 + wv * 16 + lrow) * HD + lq * 8;
    qf0 = *(const short8*)qp;
    qf1 = *(const short8*)(qp + 32);
  }

  f32x4 o[4] = {};
  float mrun[4], lrun[4];
#pragma unroll
  for (int r = 0; r < 4; ++r) { mrun[r] = -1e30f; lrun[r] = 0.f; }

  const int rstg = wv * 8 + (ln >> 3);
  const int ustg = (ln & 7) ^ (ln >> 3);

  for (int t = 0; t < L_SEQ / 64; ++t) {
    const int t0 = t * 64;
#pragma unroll
    for (int i = 0; i < 2; ++i) {
      int r = i * 32 + rstg;
      GLOAD_LDS16(Kb + ((size_t)h * L_SEQ + t0 + r) * HD + (ustg << 3), Ks + i * 2048 + wv * 512);
      GLOAD_LDS16(Vt + ((size_t)(h * HD + r)) * L_SEQ + t0 + (ustg << 3), Vs + i * 2048 + wv * 512);
    }
    __syncthreads();

    // S = Q K^T  (rows q, cols key)
    f32x4 sfr[4] = {};
    __builtin_amdgcn_s_setprio(1);
#pragma unroll
    for (int ks = 0; ks < 2; ++ks) {
      short8 qa = ks ? qf1 : qf0;
#pragma unroll
      for (int f = 0; f < 4; ++f) {
        int key = f * 16 + lrow;
        int u = (ks * 4 + lq) ^ (key & 7);
        short8 kb = *(const short8*)(Ks + key * 64 + (u << 3));
        sfr[f] = __builtin_amdgcn_mfma_f32_16x16x32_bf16(qa, kb, sfr[f], 0, 0, 0);
      }
    }
    __builtin_amdgcn_s_setprio(0);

    // base-2 logits + log2(size_key)
#pragma unroll
    for (int f = 0; f < 4; ++f) {
      float bias = l2s[t0 + f * 16 + lrow];
#pragma unroll
      for (int r = 0; r < 4; ++r)
        sfr[f][r] = sfr[f][r] * LOG2E + bias;
    }

    // online softmax; row r lives in 16-lane group (lanes share lq)
    float alpha[4];
    bool noop = true;
#pragma unroll
    for (int r = 0; r < 4; ++r) {
      float t1 = fmaxf(fmaxf(sfr[0][r], sfr[1][r]), fmaxf(sfr[2][r], sfr[3][r]));
      t1 = red16_max(t1);                        // DPP butterfly (VALU pipe)
      float mnew = fmaxf(mrun[r], t1);
      alpha[r] = __builtin_amdgcn_exp2f(mrun[r] - mnew);
      mrun[r] = mnew;
      float rs = 0.f;
#pragma unroll
      for (int f = 0; f < 4; ++f) {
        float pv = __builtin_amdgcn_exp2f(sfr[f][r] - mnew);
        sfr[f][r] = pv;
        rs += pv;
      }
      rs = red16_sum(rs);                        // DPP butterfly (VALU pipe)
      lrun[r] = lrun[r] * alpha[r] + rs;
      noop = noop && (alpha[r] == 1.0f);
    }
    if (!__all(noop)) {              // skip O-rescale when all alphas == 1
#pragma unroll
      for (int df = 0; df < 4; ++df)
#pragma unroll
        for (int r = 0; r < 4; ++r) o[df][r] *= alpha[r];
    }

    // P -> per-wave LDS (C layout in, A layout out), padded to 72 shorts/row
    ushortT* pb = &Ps[wv][0];
#pragma unroll
    for (int f = 0; f < 4; ++f)
#pragma unroll
      for (int r = 0; r < 4; ++r)
        pb[(lq * 4 + r) * 72 + f * 16 + lrow] = f2bf(sfr[f][r]);

    asm volatile("s_waitcnt lgkmcnt(0)" ::: "memory");  // cross-lane LDS dep
    __builtin_amdgcn_sched_barrier(0);

    short8 pa0 = *(const short8*)(pb + lrow * 72 + lq * 8);
    short8 pa1 = *(const short8*)(pb + lrow * 72 + 32 + lq * 8);

    // O += P @ V   (B operand from transposed-V tile: row=d, k=key)
    __builtin_amdgcn_s_setprio(1);
#pragma unroll
    for (int ks = 0; ks < 2; ++ks) {
      short8 pa = ks ? pa1 : pa0;
#pragma unroll
      for (int df = 0; df < 4; ++df) {
        int d = df * 16 + lrow;
        int u = (ks * 4 + lq) ^ (d & 7);
        short8 vb = *(const short8*)(Vs + d * 64 + (u << 3));
        o[df] = __builtin_amdgcn_mfma_f32_16x16x32_bf16(pa, vb, o[df], 0, 0, 0);
      }
    }
    __builtin_amdgcn_s_setprio(0);

    __syncthreads();
  }

  // epilogue: divide by softmax denom, store bf16 [t][h*64+d]
#pragma unroll
  for (int df = 0; df < 4; ++df)
#pragma unroll
    for (int r = 0; r < 4; ++r) {
      int q = q0 + wv * 16 + lq * 4 + r;
      O[(size_t)q * EMBED + h * HD + df * 16 + lrow] = f2bf(o[df][r] / lrun[r]);
    }
}

// ---------------- metric = mean over heads of K ----------------
__global__ void metric_k(const ushortT* __restrict__ Kb, float* __restrict__ out) {
  int idx = blockIdx.x * blockDim.x + threadIdx.x;   // t*8 + c8
  int t = idx >> 3, c8 = idx & 7;
  float acc[8] = {};
#pragma unroll
  for (int h = 0; h < HEADS; ++h) {
    short8 v = *(const short8*)(Kb + ((size_t)h * L_SEQ + t) * HD + c8 * 8);
#pragma unroll
    for (int j = 0; j < 8; ++j) acc[j] += bf2f((ushortT)v[j]);
  }
  float* dst = out + (size_t)t * HD + c8 * 8;
#pragma unroll
  for (int j = 0; j < 8; ++j) dst[j] = acc[j] * (1.0f / 16.0f);
}

extern "C" void kernel_launch(void* const* d_in, const int* in_sizes, int n_in,
                              void* d_out, int out_size, void* d_ws, size_t ws_size,
                              hipStream_t stream) {
  const float* hs = (const float*)d_in[0];
  const float* sz = (const float*)d_in[1];
  const float* wq = (const float*)d_in[2];
  const float* bq = (const float*)d_in[3];
  const float* wk = (const float*)d_in[4];
  const float* bk = (const float*)d_in[5];
  const float* wv = (const float*)d_in[6];
  const float* bv = (const float*)d_in[7];
  const float* wo = (const float*)d_in[8];
  const float* bo = (const float*)d_in[9];

  char* ws = (char*)d_ws;
  ushortT* hs_b = (ushortT*)(ws);                 // [4096][1024] bf16
  ushortT* wq_b = (ushortT*)(ws + (8u << 20));    // 4 weights bf16 (contiguous)
  ushortT* wk_b = wq_b + (1u << 20);
  ushortT* wv_b = wq_b + (2u << 20);
  ushortT* wo_b = wq_b + (3u << 20);
  ushortT* q_b  = (ushortT*)(ws + (16u << 20));   // [16][4096][64]
  ushortT* k_b  = (ushortT*)(ws + (24u << 20));   // [16][4096][64]
  ushortT* vt_b = (ushortT*)(ws + (32u << 20));   // [16][64][4096]
  ushortT* at_b = (ushortT*)(ws + (40u << 20));   // [4096][1024]
  float*   l2s  = (float*)(ws + (48u << 20));     // [4096]

  float* outp    = (float*)d_out;
  float* metricp = outp + (size_t)L_SEQ * EMBED;

  cast_bf16_k<<<L_SEQ * EMBED / 8 / 256, 256, 0, stream>>>(hs, hs_b, L_SEQ * EMBED / 8);
  cast4_bf16_k<<<2048, 256, 0, stream>>>(wq, wk, wv, wo, wq_b);
  l2size_k<<<L_SEQ / 256, 256, 0, stream>>>(sz, l2s, L_SEQ);

  GemmArgs aq{wq_b, bq, (void*)q_b, 0};
  GemmArgs ak{wk_b, bk, (void*)k_b, 1};
  GemmArgs av{wv_b, bv, (void*)vt_b, 2};
  gemm_bt_k<<<dim3(256, 3), 256, 0, stream>>>(hs_b, aq, ak, av);   // fused QKV

  metric_k<<<L_SEQ * 8 / 256, 256, 0, stream>>>(k_b, metricp);

  attn_k<<<1024, 256, 0, stream>>>(q_b, k_b, vt_b, l2s, at_b);

  GemmArgs ao{wo_b, bo, (void*)outp, 3};
  gemm_bt_k<<<dim3(256, 1), 256, 0, stream>>>(at_b, ao, ao, ao);   // O projection
}